// Round 1
// baseline (1385.984 us; speedup 1.0000x reference)
//
#include <hip/hip_runtime.h>

#define HID 256
#define BM 64
#define BK 16
#define LN_EPS 1e-5f
#define DENOM_EPS 1e-8f

__device__ inline void fma4(float4& c, float a, const float4& b) {
    c.x = fmaf(a, b.x, c.x);
    c.y = fmaf(a, b.y, c.y);
    c.z = fmaf(a, b.z, c.z);
    c.w = fmaf(a, b.w, c.w);
}

// K1: h0 = 0.5*(ft@wt + fi@wi), h0[0,:]=0.  BM=64 rows x full 256 cols per block.
// 256 threads: tn=t&63 -> cols tn*4..+3, tm=t>>6 -> rows tm*16..+15 (acc 16 x float4)
__global__ __launch_bounds__(256) void k1_h0(
    const float* __restrict__ ft, const float* __restrict__ fi,
    const float* __restrict__ wt, const float* __restrict__ wi,
    float* __restrict__ h0, int N)
{
    __shared__ float As[BK][BM + 4];   // [k][m], stride 68 -> 2-way-max bank conflict on transpose store
    __shared__ float Bs[BK][HID];
    const int t = threadIdx.x;
    const int tn = t & 63;
    const int tm = t >> 6;
    const int m0 = blockIdx.x * BM;
    const int lrow = t >> 2;          // A-load row 0..63
    const int kc = (t & 3) * 4;       // A-load k-chunk
    const int gr_l = m0 + lrow;

    float4 acc[16];
#pragma unroll
    for (int i = 0; i < 16; ++i) acc[i] = make_float4(0.f, 0.f, 0.f, 0.f);

    for (int seg = 0; seg < 2; ++seg) {
        const float* __restrict__ A = seg ? fi : ft;
        const float* __restrict__ B = seg ? wi : wt;
        const int K = seg ? 512 : 384;
        for (int k0 = 0; k0 < K; k0 += BK) {
            __syncthreads();
            // A tile 64x16, transposed store
            float4 av = make_float4(0.f, 0.f, 0.f, 0.f);
            if (gr_l < N) av = *(const float4*)(A + (size_t)gr_l * K + (k0 + kc));
            As[kc + 0][lrow] = av.x;
            As[kc + 1][lrow] = av.y;
            As[kc + 2][lrow] = av.z;
            As[kc + 3][lrow] = av.w;
            // B tile 16x256
#pragma unroll
            for (int p = 0; p < 4; ++p) {
                int idx = p * 256 + t;
                int br = idx >> 6;
                int bc = (idx & 63) * 4;
                *(float4*)&Bs[br][bc] = *(const float4*)(B + (size_t)(k0 + br) * HID + bc);
            }
            __syncthreads();
#pragma unroll
            for (int k = 0; k < BK; ++k) {
                float4 b = *(const float4*)&Bs[k][tn * 4];
#pragma unroll
                for (int i4 = 0; i4 < 4; ++i4) {
                    float4 a = *(const float4*)&As[k][tm * 16 + i4 * 4];
                    fma4(acc[i4 * 4 + 0], a.x, b);
                    fma4(acc[i4 * 4 + 1], a.y, b);
                    fma4(acc[i4 * 4 + 2], a.z, b);
                    fma4(acc[i4 * 4 + 3], a.w, b);
                }
            }
        }
    }
#pragma unroll
    for (int i = 0; i < 16; ++i) {
        int gr = m0 + tm * 16 + i;
        if (gr < N) {
            float4 v = make_float4(acc[i].x * 0.5f, acc[i].y * 0.5f,
                                   acc[i].z * 0.5f, acc[i].w * 0.5f);
            if (gr == 0) v = make_float4(0.f, 0.f, 0.f, 0.f);
            *(float4*)(h0 + (size_t)gr * HID + tn * 4) = v;
        }
    }
}

// K2: one wave per edge: S[type][dst][:] += w * h0[src][:];  denom[type][dst] += w
__global__ __launch_bounds__(256) void k2_scatter(
    const float* __restrict__ h0, const int* __restrict__ eidx,
    const int* __restrict__ etype, const float* __restrict__ ew,
    float* __restrict__ S, float* __restrict__ denomv, int E, int N)
{
    int gid = blockIdx.x * 256 + threadIdx.x;
    int e = gid >> 6;
    int lane = gid & 63;
    if (e >= E) return;
    int src = eidx[e];
    int dst = eidx[E + e];
    int ty = etype[e];
    float w = ew[e];
    const float* hrow = h0 + (size_t)src * HID;
    float* srow = S + ((size_t)ty * N + dst) * HID;
#pragma unroll
    for (int j = 0; j < 4; ++j) {
        int c = lane + j * 64;
        atomicAdd(&srow[c], w * hrow[c]);
    }
    if (lane == 0) atomicAdd(&denomv[(size_t)ty * N + dst], w);
}

// K3: out = LN(h0 + sum_rel (S_rel/denom_rel) @ W_rel) * gamma + beta; out[0,:]=0
// Same tiling as K1; K = 768 (=3 rels x 256). LN done per-row fully in-wave.
__global__ __launch_bounds__(256) void k3_agg_ln(
    const float* __restrict__ S, const float* __restrict__ denomv,
    const float* __restrict__ wrel,   // [768][256]
    const float* __restrict__ h0,     // aliases out (read-before-write per element)
    const float* __restrict__ gamma, const float* __restrict__ beta,
    float* __restrict__ out, int N)
{
    __shared__ float As[BK][BM + 4];
    __shared__ float Bs[BK][HID];
    const int t = threadIdx.x;
    const int tn = t & 63;
    const int tm = t >> 6;
    const int m0 = blockIdx.x * BM;
    const int lrow = t >> 2;
    const int kc = (t & 3) * 4;
    const int gr_l = m0 + lrow;

    float dinv[3];
#pragma unroll
    for (int r = 0; r < 3; ++r) {
        float d = (gr_l < N) ? denomv[(size_t)r * N + gr_l] : 1.0f;
        dinv[r] = 1.0f / fmaxf(d, DENOM_EPS);
    }

    float4 acc[16];
#pragma unroll
    for (int i = 0; i < 16; ++i) acc[i] = make_float4(0.f, 0.f, 0.f, 0.f);

    for (int tile = 0; tile < 48; ++tile) {
        const int kg = tile * BK;        // global K index, rel = kg>>8
        const int rel = kg >> 8;
        __syncthreads();
        float4 av = make_float4(0.f, 0.f, 0.f, 0.f);
        if (gr_l < N)
            av = *(const float4*)(S + ((size_t)rel * N + gr_l) * HID + (kg & 255) + kc);
        const float dv = dinv[rel];
        As[kc + 0][lrow] = av.x * dv;
        As[kc + 1][lrow] = av.y * dv;
        As[kc + 2][lrow] = av.z * dv;
        As[kc + 3][lrow] = av.w * dv;
#pragma unroll
        for (int p = 0; p < 4; ++p) {
            int idx = p * 256 + t;
            int br = idx >> 6;
            int bc = (idx & 63) * 4;
            *(float4*)&Bs[br][bc] = *(const float4*)(wrel + (size_t)(kg + br) * HID + bc);
        }
        __syncthreads();
#pragma unroll
        for (int k = 0; k < BK; ++k) {
            float4 b = *(const float4*)&Bs[k][tn * 4];
#pragma unroll
            for (int i4 = 0; i4 < 4; ++i4) {
                float4 a = *(const float4*)&As[k][tm * 16 + i4 * 4];
                fma4(acc[i4 * 4 + 0], a.x, b);
                fma4(acc[i4 * 4 + 1], a.y, b);
                fma4(acc[i4 * 4 + 2], a.z, b);
                fma4(acc[i4 * 4 + 3], a.w, b);
            }
        }
    }

    const int colbase = tn * 4;
    const float4 g4 = *(const float4*)(gamma + colbase);
    const float4 b4 = *(const float4*)(beta + colbase);
#pragma unroll
    for (int i = 0; i < 16; ++i) {
        int row = m0 + tm * 16 + i;       // wave-uniform
        if (row >= N) continue;
        float4 h = *(const float4*)(h0 + (size_t)row * HID + colbase);
        float4 x = acc[i];
        x.x += h.x; x.y += h.y; x.z += h.z; x.w += h.w;
        float s  = x.x + x.y + x.z + x.w;
        float s2 = x.x * x.x + x.y * x.y + x.z * x.z + x.w * x.w;
#pragma unroll
        for (int off = 32; off; off >>= 1) {
            s  += __shfl_xor(s, off, 64);
            s2 += __shfl_xor(s2, off, 64);
        }
        float mu  = s * (1.0f / 256.0f);
        float var = s2 * (1.0f / 256.0f) - mu * mu;
        float rstd = rsqrtf(var + LN_EPS);
        float4 o;
        o.x = (x.x - mu) * rstd * g4.x + b4.x;
        o.y = (x.y - mu) * rstd * g4.y + b4.y;
        o.z = (x.z - mu) * rstd * g4.z + b4.z;
        o.w = (x.w - mu) * rstd * g4.w + b4.w;
        if (row == 0) o = make_float4(0.f, 0.f, 0.f, 0.f);
        *(float4*)(out + (size_t)row * HID + colbase) = o;
    }
}

extern "C" void kernel_launch(void* const* d_in, const int* in_sizes, int n_in,
                              void* d_out, int out_size, void* d_ws, size_t ws_size,
                              hipStream_t stream) {
    const int N = in_sizes[0] / 384;   // 100000
    const int E = in_sizes[7];         // 300000
    const float* ft    = (const float*)d_in[0];
    const float* fi    = (const float*)d_in[1];
    const float* wt    = (const float*)d_in[2];
    const float* wi    = (const float*)d_in[3];
    const float* wrel  = (const float*)d_in[4];
    const float* gamma = (const float*)d_in[5];
    const float* beta  = (const float*)d_in[6];
    const float* ew    = (const float*)d_in[7];
    const int*   eidx  = (const int*)d_in[8];
    const int*   etype = (const int*)d_in[9];
    float* out = (float*)d_out;

    float* S      = (float*)d_ws;                    // [3][N][256]
    float* denomv = S + (size_t)3 * N * HID;         // [3][N]
    size_t zbytes = ((size_t)3 * N * HID + (size_t)3 * N) * sizeof(float);
    hipMemsetAsync(d_ws, 0, zbytes, stream);

    const int mblocks = (N + BM - 1) / BM;           // 1563
    k1_h0<<<mblocks, 256, 0, stream>>>(ft, fi, wt, wi, out, N);

    const int sblocks = (E + 3) / 4;                 // 4 edges (waves) per 256-thr block
    k2_scatter<<<sblocks, 256, 0, stream>>>(out, eidx, etype, ew, S, denomv, E, N);

    k3_agg_ln<<<mblocks, 256, 0, stream>>>(S, denomv, wrel, out, gamma, beta, out, N);
}

// Round 2
// 648.843 us; speedup vs baseline: 2.1361x; 2.1361x over previous
//
#include <hip/hip_runtime.h>
#include <hip/hip_bf16.h>

#define HID 256
#define LN_EPS 1e-5f
#define DENOM_EPS 1e-8f

typedef __attribute__((ext_vector_type(8))) short short8;
typedef __attribute__((ext_vector_type(4))) float f32x4;

#define WP1_ELEMS (28 * 256 * 32)   // K=896 packed, pre-scaled by 0.5
#define WP2_ELEMS (24 * 256 * 32)   // K=768 (3 rels x 256)

__device__ inline unsigned bfpk(float x, float y) {
    __hip_bfloat162 h = __float22bfloat162_rn(make_float2(x, y));
    return *reinterpret_cast<unsigned*>(&h);
}

// Pack weights into fragment-native layout: wp[ks][col][kk] = W[ks*32+kk][col] (*0.5 for wp1)
__global__ __launch_bounds__(256) void kpack(
    const float* __restrict__ wt, const float* __restrict__ wi,
    const float* __restrict__ wrel,
    __hip_bfloat16* __restrict__ wp1, __hip_bfloat16* __restrict__ wp2)
{
    int idx = blockIdx.x * 256 + threadIdx.x;
    if (idx < WP1_ELEMS) {
        int kk = idx & 31, col = (idx >> 5) & 255, ks = idx >> 13;
        int k = ks * 32 + kk;
        float v = (k < 384) ? wt[k * 256 + col] : wi[(k - 384) * 256 + col];
        wp1[idx] = __float2bfloat16(v * 0.5f);
    } else {
        int j = idx - WP1_ELEMS;
        if (j < WP2_ELEMS) {
            int kk = j & 31, col = (j >> 5) & 255, ks = j >> 13;
            int k = ks * 32 + kk;                 // wrel flat [768][256]
            wp2[j] = __float2bfloat16(wrel[k * 256 + col]);
        }
    }
}

// K2: one wave per edge: S[type][dst][:] += w * h0[src][:];  denom[type][dst] += w
__global__ __launch_bounds__(256) void k2_scatter(
    const float* __restrict__ h0, const int* __restrict__ eidx,
    const int* __restrict__ etype, const float* __restrict__ ew,
    float* __restrict__ S, float* __restrict__ denomv, int E, int N)
{
    int gid = blockIdx.x * 256 + threadIdx.x;
    int e = gid >> 6;
    int lane = gid & 63;
    if (e >= E) return;
    int src = eidx[e];
    int dst = eidx[E + e];
    int ty = etype[e];
    float w = ew[e];
    const float* hrow = h0 + (size_t)src * HID;
    float* srow = S + ((size_t)ty * N + dst) * HID;
#pragma unroll
    for (int j = 0; j < 4; ++j) {
        int c = lane + j * 64;
        atomicAdd(&srow[c], w * hrow[c]);
    }
    if (lane == 0) atomicAdd(&denomv[(size_t)ty * N + dst], w);
}

// MFMA GEMM, block tile 128x256, 8 waves (2 row-groups x 4 col-groups), wave tile 64x64.
// MODE 0: out = 0.5*(ft@wt + fi@wi)  (0.5 folded into wp1), row 0 zeroed.
// MODE 1: out = LN(h0 + concat_rel(S_rel * dinv_rel) @ wp2), row 0 zeroed. h0in aliases out.
template<int MODE>
__global__ __launch_bounds__(512) void kgemm(
    const float* __restrict__ a0, const float* __restrict__ a1,
    const __hip_bfloat16* __restrict__ wp,
    const float* h0in, const float* __restrict__ gamma,
    const float* __restrict__ beta, float* out, int N)
{
    constexpr int NSTEPS = MODE ? 24 : 28;
    __shared__ __align__(16) unsigned char As[128 * 80];  // bf16 [row][32k], 80B-padded rows
    __shared__ float redS[128][4];
    __shared__ float redQ[128][4];

    const int t = threadIdx.x;
    const int lane = t & 63;
    const int w = t >> 6;
    const int wr = w >> 2, wc = w & 3;
    const int m0 = blockIdx.x * 128;

    // staging: iter i covers rows srow0 + i*64; 8 threads/row, 4 f32 each
    const int srow0 = t >> 3, sub = t & 7;

    float dinv[2][3];
    if constexpr (MODE == 1) {
#pragma unroll
        for (int i = 0; i < 2; ++i) {
            int grow = m0 + srow0 + i * 64;
#pragma unroll
            for (int r = 0; r < 3; ++r) {
                float d = (grow < N) ? a1[(size_t)r * N + grow] : 1.0f;
                dinv[i][r] = 1.0f / fmaxf(d, DENOM_EPS);
            }
        }
    }

    f32x4 acc[4][4];
#pragma unroll
    for (int i = 0; i < 4; ++i)
#pragma unroll
        for (int j = 0; j < 4; ++j) acc[i][j] = (f32x4){0.f, 0.f, 0.f, 0.f};

    for (int ks = 0; ks < NSTEPS; ++ks) {
        __syncthreads();
#pragma unroll
        for (int i = 0; i < 2; ++i) {
            int srow = srow0 + i * 64;
            int grow = m0 + srow;
            float4 v = make_float4(0.f, 0.f, 0.f, 0.f);
            if constexpr (MODE == 0) {
                if (grow < N) {
                    if (ks < 12) v = *(const float4*)(a0 + (size_t)grow * 384 + ks * 32 + sub * 4);
                    else         v = *(const float4*)(a1 + (size_t)grow * 512 + (ks - 12) * 32 + sub * 4);
                }
            } else {
                int rel = ks >> 3;
                if (grow < N) {
                    v = *(const float4*)(a0 + ((size_t)rel * N + grow) * 256 + (ks & 7) * 32 + sub * 4);
                    float sc = dinv[i][rel];
                    v.x *= sc; v.y *= sc; v.z *= sc; v.w *= sc;
                }
            }
            unsigned p0 = bfpk(v.x, v.y), p1 = bfpk(v.z, v.w);
            *(uint2*)(As + srow * 80 + sub * 8) = make_uint2(p0, p1);
        }
        __syncthreads();

        short8 af[4], bf[4];
#pragma unroll
        for (int fr = 0; fr < 4; ++fr)
            af[fr] = *(const short8*)(As + (wr * 64 + fr * 16 + (lane & 15)) * 80 + (lane >> 4) * 16);
#pragma unroll
        for (int fc = 0; fc < 4; ++fc)
            bf[fc] = *(const short8*)((const short*)wp +
                      (size_t)(ks * 256 + wc * 64 + fc * 16 + (lane & 15)) * 32 + (lane >> 4) * 8);
#pragma unroll
        for (int fr = 0; fr < 4; ++fr)
#pragma unroll
            for (int fc = 0; fc < 4; ++fc)
                acc[fr][fc] = __builtin_amdgcn_mfma_f32_16x16x32_bf16(af[fr], bf[fc], acc[fr][fc], 0, 0, 0);
    }

    const int rbase = m0 + wr * 64;
    const int cbase = wc * 64;

    if constexpr (MODE == 0) {
#pragma unroll
        for (int fr = 0; fr < 4; ++fr)
#pragma unroll
            for (int reg = 0; reg < 4; ++reg) {
                int grow = rbase + fr * 16 + (lane >> 4) * 4 + reg;
                if (grow >= N) continue;
#pragma unroll
                for (int fc = 0; fc < 4; ++fc) {
                    float vv = acc[fr][fc][reg];
                    if (grow == 0) vv = 0.f;
                    out[(size_t)grow * 256 + cbase + fc * 16 + (lane & 15)] = vv;
                }
            }
    } else {
        // x = acc + h0 (same-thread read-before-write; out aliases h0in)
#pragma unroll
        for (int fr = 0; fr < 4; ++fr)
#pragma unroll
            for (int reg = 0; reg < 4; ++reg) {
                int grow = rbase + fr * 16 + (lane >> 4) * 4 + reg;
                if (grow < N) {
#pragma unroll
                    for (int fc = 0; fc < 4; ++fc)
                        acc[fr][fc][reg] += h0in[(size_t)grow * 256 + cbase + fc * 16 + (lane & 15)];
                }
            }
        // per-row partials: sum over this wave's 64 cols (4 fc frags x 16 lanes)
#pragma unroll
        for (int fr = 0; fr < 4; ++fr)
#pragma unroll
            for (int reg = 0; reg < 4; ++reg) {
                float s = 0.f, q = 0.f;
#pragma unroll
                for (int fc = 0; fc < 4; ++fc) {
                    float vv = acc[fr][fc][reg];
                    s += vv; q += vv * vv;
                }
#pragma unroll
                for (int off = 1; off < 16; off <<= 1) {
                    s += __shfl_xor(s, off, 64);
                    q += __shfl_xor(q, off, 64);
                }
                if ((lane & 15) == 0) {
                    int rl = wr * 64 + fr * 16 + (lane >> 4) * 4 + reg;
                    redS[rl][wc] = s;
                    redQ[rl][wc] = q;
                }
            }
        __syncthreads();
        float g4[4], b4[4];
#pragma unroll
        for (int fc = 0; fc < 4; ++fc) {
            g4[fc] = gamma[cbase + fc * 16 + (lane & 15)];
            b4[fc] = beta[cbase + fc * 16 + (lane & 15)];
        }
#pragma unroll
        for (int fr = 0; fr < 4; ++fr)
#pragma unroll
            for (int reg = 0; reg < 4; ++reg) {
                int rl = wr * 64 + fr * 16 + (lane >> 4) * 4 + reg;
                int grow = m0 + rl;
                if (grow >= N) continue;
                float s = redS[rl][0] + redS[rl][1] + redS[rl][2] + redS[rl][3];
                float q = redQ[rl][0] + redQ[rl][1] + redQ[rl][2] + redQ[rl][3];
                float mu  = s * (1.f / 256.f);
                float var = q * (1.f / 256.f) - mu * mu;
                float rstd = rsqrtf(var + LN_EPS);
#pragma unroll
                for (int fc = 0; fc < 4; ++fc) {
                    float vv = (acc[fr][fc][reg] - mu) * rstd * g4[fc] + b4[fc];
                    if (grow == 0) vv = 0.f;
                    out[(size_t)grow * 256 + cbase + fc * 16 + (lane & 15)] = vv;
                }
            }
    }
}

extern "C" void kernel_launch(void* const* d_in, const int* in_sizes, int n_in,
                              void* d_out, int out_size, void* d_ws, size_t ws_size,
                              hipStream_t stream) {
    const int N = in_sizes[0] / 384;   // 100000
    const int E = in_sizes[7];         // 300000
    const float* ft    = (const float*)d_in[0];
    const float* fi    = (const float*)d_in[1];
    const float* wt    = (const float*)d_in[2];
    const float* wi    = (const float*)d_in[3];
    const float* wrel  = (const float*)d_in[4];
    const float* gamma = (const float*)d_in[5];
    const float* beta  = (const float*)d_in[6];
    const float* ew    = (const float*)d_in[7];
    const int*   eidx  = (const int*)d_in[8];
    const int*   etype = (const int*)d_in[9];
    float* out = (float*)d_out;

    float* S      = (float*)d_ws;                        // [3][N][256] f32
    float* denomv = S + (size_t)3 * N * HID;             // [3][N] f32
    __hip_bfloat16* wp1 = (__hip_bfloat16*)(denomv + (size_t)3 * N);
    __hip_bfloat16* wp2 = wp1 + WP1_ELEMS;

    size_t zbytes = ((size_t)3 * N * HID + (size_t)3 * N) * sizeof(float);
    hipMemsetAsync(d_ws, 0, zbytes, stream);

    kpack<<<(WP1_ELEMS + WP2_ELEMS + 255) / 256, 256, 0, stream>>>(wt, wi, wrel, wp1, wp2);

    const int gblocks = (N + 127) / 128;                 // 782
    kgemm<0><<<gblocks, 512, 0, stream>>>(ft, fi, wp1, nullptr, nullptr, nullptr, out, N);

    const int sblocks = (E + 3) / 4;                     // 4 edges (waves) per block
    k2_scatter<<<sblocks, 256, 0, stream>>>(out, eidx, etype, ew, S, denomv, E, N);

    kgemm<1><<<gblocks, 512, 0, stream>>>(S, denomv, wp2, out, gamma, beta, out, N);
}

// Round 3
// 396.845 us; speedup vs baseline: 3.4925x; 1.6350x over previous
//
#include <hip/hip_runtime.h>
#include <hip/hip_bf16.h>

#define HID 256
#define LN_EPS 1e-5f
#define DENOM_EPS 1e-8f

typedef __attribute__((ext_vector_type(8))) short short8;
typedef __attribute__((ext_vector_type(4))) float f32x4;

#define WP1_ELEMS (28 * 256 * 32)   // K=896 packed, pre-scaled by 0.5
#define WP2_ELEMS (24 * 256 * 32)   // K=768 (3 rels x 256)

__device__ inline unsigned bfpk(float x, float y) {
    __hip_bfloat162 h = __float22bfloat162_rn(make_float2(x, y));
    return *reinterpret_cast<unsigned*>(&h);
}

// Pack weights into fragment-native layout: wp[ks][col][kk] = W[ks*32+kk][col] (*0.5 for wp1)
__global__ __launch_bounds__(256) void kpack(
    const float* __restrict__ wt, const float* __restrict__ wi,
    const float* __restrict__ wrel,
    __hip_bfloat16* __restrict__ wp1, __hip_bfloat16* __restrict__ wp2)
{
    int idx = blockIdx.x * 256 + threadIdx.x;
    if (idx < WP1_ELEMS) {
        int kk = idx & 31, col = (idx >> 5) & 255, ks = idx >> 13;
        int k = ks * 32 + kk;
        float v = (k < 384) ? wt[k * 256 + col] : wi[(k - 384) * 256 + col];
        wp1[idx] = __float2bfloat16(v * 0.5f);
    } else {
        int j = idx - WP1_ELEMS;
        if (j < WP2_ELEMS) {
            int kk = j & 31, col = (j >> 5) & 255, ks = j >> 13;
            int k = ks * 32 + kk;                 // wrel flat [768][256]
            wp2[j] = __float2bfloat16(wrel[k * 256 + col]);
        }
    }
}

// Build per-dst edge chains: next[e] = atomicExch(head[dst], e). head pre-inited to -1.
__global__ __launch_bounds__(256) void kchain(
    const int* __restrict__ edst, int* __restrict__ head, int* __restrict__ nxt, int E)
{
    int e = blockIdx.x * 256 + threadIdx.x;
    if (e < E) nxt[e] = atomicExch(&head[edst[e]], e);
}

// One wave per dst node: walk chain, acc[rel] += w*h0[src], then
// S[d][rel*256+c] = bf16(acc[rel][c] / max(denom[rel], eps)).  No atomics, no memset of S.
__global__ __launch_bounds__(256) void k2_gather(
    const float* __restrict__ h0, const int* __restrict__ esrc,
    const int* __restrict__ etype, const float* __restrict__ ew,
    const int* __restrict__ head, const int* __restrict__ nxt,
    __hip_bfloat16* __restrict__ S, int N)
{
    int gid = blockIdx.x * 256 + threadIdx.x;
    int d = gid >> 6;
    int lane = gid & 63;
    if (d >= N) return;

    f32x4 a0 = {0.f, 0.f, 0.f, 0.f}, a1 = a0, a2 = a0;
    float d0 = 0.f, d1 = 0.f, d2 = 0.f;

    int e = head[d];
    while (e >= 0) {
        int src = esrc[e];
        int ty = etype[e];       // wave-uniform
        float w = ew[e];
        const float4 h = *(const float4*)(h0 + (size_t)src * HID + lane * 4);
        f32x4 hw = {w * h.x, w * h.y, w * h.z, w * h.w};
        if (ty == 0)      { a0 += hw; d0 += w; }
        else if (ty == 1) { a1 += hw; d1 += w; }
        else              { a2 += hw; d2 += w; }
        e = nxt[e];
    }

    float i0 = 1.0f / fmaxf(d0, DENOM_EPS);
    float i1 = 1.0f / fmaxf(d1, DENOM_EPS);
    float i2 = 1.0f / fmaxf(d2, DENOM_EPS);
    __hip_bfloat16* row = S + (size_t)d * 768;
    uint2 p;
    p = make_uint2(bfpk(a0[0] * i0, a0[1] * i0), bfpk(a0[2] * i0, a0[3] * i0));
    *(uint2*)(row + 0   + lane * 4) = p;
    p = make_uint2(bfpk(a1[0] * i1, a1[1] * i1), bfpk(a1[2] * i1, a1[3] * i1));
    *(uint2*)(row + 256 + lane * 4) = p;
    p = make_uint2(bfpk(a2[0] * i2, a2[1] * i2), bfpk(a2[2] * i2, a2[3] * i2));
    *(uint2*)(row + 512 + lane * 4) = p;
}

// MFMA GEMM, block tile 128x256, 8 waves (2x4), wave tile 64x64.
// MODE 0: out = ft@wp1a + fi@wp1b (0.5 pre-folded), row 0 zeroed. A: f32, convert on stage.
// MODE 1: out = LN(h0 + Sb@wp2), row 0 zeroed. A: bf16 [N][768], direct copy. h0in aliases out.
template<int MODE>
__global__ __launch_bounds__(512) void kgemm(
    const float* __restrict__ a0, const float* __restrict__ a1,
    const __hip_bfloat16* __restrict__ Sb,
    const __hip_bfloat16* __restrict__ wp,
    const float* h0in, const float* __restrict__ gamma,
    const float* __restrict__ beta, float* out, int N)
{
    constexpr int NSTEPS = MODE ? 24 : 28;
    __shared__ __align__(16) unsigned char As[128 * 80];  // bf16 [row][32k], 80B-padded rows
    __shared__ float redS[128][4];
    __shared__ float redQ[128][4];

    const int t = threadIdx.x;
    const int lane = t & 63;
    const int w = t >> 6;
    const int wr = w >> 2, wc = w & 3;
    const int m0 = blockIdx.x * 128;

    f32x4 acc[4][4];
#pragma unroll
    for (int i = 0; i < 4; ++i)
#pragma unroll
        for (int j = 0; j < 4; ++j) acc[i][j] = (f32x4){0.f, 0.f, 0.f, 0.f};

    for (int ks = 0; ks < NSTEPS; ++ks) {
        __syncthreads();
        if constexpr (MODE == 0) {
            const int srow0 = t >> 3, sub = t & 7;   // 8 thr/row, 4 f32 each
#pragma unroll
            for (int i = 0; i < 2; ++i) {
                int srow = srow0 + i * 64;
                int grow = m0 + srow;
                float4 v = make_float4(0.f, 0.f, 0.f, 0.f);
                if (grow < N) {
                    if (ks < 12) v = *(const float4*)(a0 + (size_t)grow * 384 + ks * 32 + sub * 4);
                    else         v = *(const float4*)(a1 + (size_t)grow * 512 + (ks - 12) * 32 + sub * 4);
                }
                *(uint2*)(As + srow * 80 + sub * 8) =
                    make_uint2(bfpk(v.x, v.y), bfpk(v.z, v.w));
            }
        } else {
            const int srow = t >> 2, sub = t & 3;    // 4 thr/row, 16B bf16 each
            int grow = m0 + srow;
            short8 v = {0, 0, 0, 0, 0, 0, 0, 0};
            if (grow < N)
                v = *(const short8*)(Sb + (size_t)grow * 768 + ks * 32 + sub * 8);
            *(short8*)(As + srow * 80 + sub * 16) = v;
        }
        __syncthreads();

        short8 af[4], bf[4];
#pragma unroll
        for (int fr = 0; fr < 4; ++fr)
            af[fr] = *(const short8*)(As + (wr * 64 + fr * 16 + (lane & 15)) * 80 + (lane >> 4) * 16);
#pragma unroll
        for (int fc = 0; fc < 4; ++fc)
            bf[fc] = *(const short8*)((const short*)wp +
                      (size_t)(ks * 256 + wc * 64 + fc * 16 + (lane & 15)) * 32 + (lane >> 4) * 8);
#pragma unroll
        for (int fr = 0; fr < 4; ++fr)
#pragma unroll
            for (int fc = 0; fc < 4; ++fc)
                acc[fr][fc] = __builtin_amdgcn_mfma_f32_16x16x32_bf16(af[fr], bf[fc], acc[fr][fc], 0, 0, 0);
    }

    const int rbase = m0 + wr * 64;
    const int cbase = wc * 64;

    if constexpr (MODE == 0) {
#pragma unroll
        for (int fr = 0; fr < 4; ++fr)
#pragma unroll
            for (int reg = 0; reg < 4; ++reg) {
                int grow = rbase + fr * 16 + (lane >> 4) * 4 + reg;
                if (grow >= N) continue;
#pragma unroll
                for (int fc = 0; fc < 4; ++fc) {
                    float vv = acc[fr][fc][reg];
                    if (grow == 0) vv = 0.f;
                    out[(size_t)grow * 256 + cbase + fc * 16 + (lane & 15)] = vv;
                }
            }
    } else {
        // x = acc + h0 (same-thread read-before-write; out aliases h0in)
#pragma unroll
        for (int fr = 0; fr < 4; ++fr)
#pragma unroll
            for (int reg = 0; reg < 4; ++reg) {
                int grow = rbase + fr * 16 + (lane >> 4) * 4 + reg;
                if (grow < N) {
#pragma unroll
                    for (int fc = 0; fc < 4; ++fc)
                        acc[fr][fc][reg] += h0in[(size_t)grow * 256 + cbase + fc * 16 + (lane & 15)];
                }
            }
#pragma unroll
        for (int fr = 0; fr < 4; ++fr)
#pragma unroll
            for (int reg = 0; reg < 4; ++reg) {
                float s = 0.f, q = 0.f;
#pragma unroll
                for (int fc = 0; fc < 4; ++fc) {
                    float vv = acc[fr][fc][reg];
                    s += vv; q += vv * vv;
                }
#pragma unroll
                for (int off = 1; off < 16; off <<= 1) {
                    s += __shfl_xor(s, off, 64);
                    q += __shfl_xor(q, off, 64);
                }
                if ((lane & 15) == 0) {
                    int rl = wr * 64 + fr * 16 + (lane >> 4) * 4 + reg;
                    redS[rl][wc] = s;
                    redQ[rl][wc] = q;
                }
            }
        __syncthreads();
        float g4[4], b4[4];
#pragma unroll
        for (int fc = 0; fc < 4; ++fc) {
            g4[fc] = gamma[cbase + fc * 16 + (lane & 15)];
            b4[fc] = beta[cbase + fc * 16 + (lane & 15)];
        }
#pragma unroll
        for (int fr = 0; fr < 4; ++fr)
#pragma unroll
            for (int reg = 0; reg < 4; ++reg) {
                int rl = wr * 64 + fr * 16 + (lane >> 4) * 4 + reg;
                int grow = m0 + rl;
                if (grow >= N) continue;
                float s = redS[rl][0] + redS[rl][1] + redS[rl][2] + redS[rl][3];
                float q = redQ[rl][0] + redQ[rl][1] + redQ[rl][2] + redQ[rl][3];
                float mu  = s * (1.f / 256.f);
                float var = q * (1.f / 256.f) - mu * mu;
                float rstd = rsqrtf(var + LN_EPS);
#pragma unroll
                for (int fc = 0; fc < 4; ++fc) {
                    float vv = (acc[fr][fc][reg] - mu) * rstd * g4[fc] + b4[fc];
                    if (grow == 0) vv = 0.f;
                    out[(size_t)grow * 256 + cbase + fc * 16 + (lane & 15)] = vv;
                }
            }
    }
}

extern "C" void kernel_launch(void* const* d_in, const int* in_sizes, int n_in,
                              void* d_out, int out_size, void* d_ws, size_t ws_size,
                              hipStream_t stream) {
    const int N = in_sizes[0] / 384;   // 100000
    const int E = in_sizes[7];         // 300000
    const float* ft    = (const float*)d_in[0];
    const float* fi    = (const float*)d_in[1];
    const float* wt    = (const float*)d_in[2];
    const float* wi    = (const float*)d_in[3];
    const float* wrel  = (const float*)d_in[4];
    const float* gamma = (const float*)d_in[5];
    const float* beta  = (const float*)d_in[6];
    const float* ew    = (const float*)d_in[7];
    const int*   eidx  = (const int*)d_in[8];
    const int*   etype = (const int*)d_in[9];
    float* out = (float*)d_out;

    // ws layout: S bf16 [N][768] | head int[N] | next int[E] | wp1 | wp2
    __hip_bfloat16* S = (__hip_bfloat16*)d_ws;
    int* head = (int*)((char*)d_ws + (size_t)N * 768 * 2);
    int* nxt  = head + N;
    __hip_bfloat16* wp1 = (__hip_bfloat16*)(nxt + E);
    __hip_bfloat16* wp2 = wp1 + WP1_ELEMS;

    hipMemsetAsync(head, 0xFF, (size_t)N * sizeof(int), stream);   // head = -1

    kpack<<<(WP1_ELEMS + WP2_ELEMS + 255) / 256, 256, 0, stream>>>(wt, wi, wrel, wp1, wp2);

    kchain<<<(E + 255) / 256, 256, 0, stream>>>(eidx + E, head, nxt, E);

    const int gblocks = (N + 127) / 128;                 // 782
    kgemm<0><<<gblocks, 512, 0, stream>>>(ft, fi, nullptr, wp1, nullptr, nullptr, nullptr, out, N);

    const int wblocks = (N + 3) / 4;                     // 1 wave per node, 4 waves/block
    k2_gather<<<wblocks, 256, 0, stream>>>(out, eidx, etype, ew, head, nxt, S, N);

    kgemm<1><<<gblocks, 512, 0, stream>>>(nullptr, nullptr, S, wp2, out, gamma, beta, out, N);
}